// Round 3
// baseline (1022.924 us; speedup 1.0000x reference)
//
#include <hip/hip_runtime.h>
#include <hip/hip_bf16.h>
#include <stdint.h>

typedef __attribute__((ext_vector_type(8))) short short8;
typedef __attribute__((ext_vector_type(4))) float floatx4;
typedef uint32_t u32;

#define N_NODES 100000
#define N_EDGES 1600000
#define ALPHA_SLOPE 0.2f
#define EPS_F 1e-16f

static __device__ __forceinline__ float bf2f(ushort h) {
    u32 u = ((u32)h) << 16;
    return __builtin_bit_cast(float, u);
}
static __device__ __forceinline__ ushort f2bf(float f) {
    u32 u = __builtin_bit_cast(u32, f);
    u32 r = (u + 0x7fffu + ((u >> 16) & 1u)) >> 16;
    return (ushort)r;
}

// ---------------- convert features f32 -> bf16 (vectorized) ----------------
__global__ __launch_bounds__(256) void conv_feat(
    const float* __restrict__ in, ushort* __restrict__ out, int n4)
{
    int i = blockIdx.x * 256 + threadIdx.x;
    if (i < n4) {
        float4 v = ((const float4*)in)[i];
        ushort4 o;
        o.x = f2bf(v.x); o.y = f2bf(v.y); o.z = f2bf(v.z); o.w = f2bf(v.w);
        ((ushort4*)out)[i] = o;
    }
}

// ---------------- pretranspose W / W_out (f32) into k-packed bf16 B layout ----------------
__global__ __launch_bounds__(256) void pretranspose(
    const float* __restrict__ W, const float* __restrict__ Wout,
    ushort* __restrict__ Bp1, ushort* __restrict__ Bp2)
{
    int idx = blockIdx.x * 256 + threadIdx.x;
    if (idx < 256 * 512) {  // Bp1: K=256, N=512
        int k = idx >> 9, n = idx & 511;
        int head = n >> 6, c = n & 63;
        Bp1[((size_t)(k >> 3) * 512 + n) * 8 + (k & 7)] = f2bf(W[head * 16384 + k * 64 + c]);
    }
    if (idx < 512 * 128) {  // Bp2: K=512, N=97 padded to 128
        int k = idx >> 7, n = idx & 127;
        ushort v = (n < 97) ? f2bf(Wout[k * 97 + n]) : (ushort)0;
        Bp2[((size_t)(k >> 3) * 128 + n) * 8 + (k & 7)] = v;
    }
}

// ---------------- MFMA GEMM: C[M,NP] = A[M,K] @ B[K,NP] (bf16 in/out, f32 acc) ----------------
__global__ __launch_bounds__(256) void gemm_mfma(
    const ushort* __restrict__ A, const ushort* __restrict__ Bp,
    ushort* __restrict__ C, int M, int K, int NP)
{
    __shared__ __align__(16) ushort Ald[4 * 128 * 8];  // [kq][r][j], 8 KB
    const int tid = threadIdx.x;
    const int lane = tid & 63;
    const int wave = tid >> 6;
    const int wr = wave >> 1, wc = wave & 1;
    const int row0 = blockIdx.x * 128;
    const int col0 = blockIdx.y * 128;
    const int quad = lane >> 4;
    const int l16 = lane & 15;

    floatx4 acc[4][4] = {};

    for (int k0 = 0; k0 < K; k0 += 32) {
        __syncthreads();
#pragma unroll
        for (int i = 0; i < 2; ++i) {
            int q = i * 256 + tid;          // 512 chunks of 16B
            int r = q >> 2, kq = q & 3;
            int row = row0 + r;
            if (row >= M) row = M - 1;      // clamp: garbage rows never stored
            const uint4* src = (const uint4*)(A + (size_t)row * K + k0 + kq * 8);
            *(uint4*)(&Ald[((kq * 128 + r) * 8)]) = *src;
        }
        __syncthreads();

        short8 bfrag[4];
        int kqg = (k0 >> 3) + quad;
#pragma unroll
        for (int nt = 0; nt < 4; ++nt) {
            int col = col0 + wc * 64 + nt * 16 + l16;
            bfrag[nt] = *(const short8*)(Bp + ((size_t)kqg * NP + col) * 8);
        }
#pragma unroll
        for (int mt = 0; mt < 4; ++mt) {
            int r = wr * 64 + mt * 16 + l16;
            short8 afrag = *(const short8*)(&Ald[(quad * 128 + r) * 8]);
#pragma unroll
            for (int nt = 0; nt < 4; ++nt) {
                acc[mt][nt] = __builtin_amdgcn_mfma_f32_16x16x32_bf16(afrag, bfrag[nt], acc[mt][nt], 0, 0, 0);
            }
        }
    }

#pragma unroll
    for (int mt = 0; mt < 4; ++mt) {
#pragma unroll
        for (int rr = 0; rr < 4; ++rr) {
            int row = row0 + wr * 64 + mt * 16 + quad * 4 + rr;
            if (row < M) {
#pragma unroll
                for (int nt = 0; nt < 4; ++nt) {
                    int col = col0 + wc * 64 + nt * 16 + l16;
                    C[(size_t)row * NP + col] = f2bf(acc[mt][nt][rr]);
                }
            }
        }
    }
}

// ---------------- per-(node,head) attention scores, layer 1 ----------------
__global__ __launch_bounds__(256) void sk1(
    const ushort* __restrict__ h_all, const float* __restrict__ a,
    float* __restrict__ ssrc, float* __restrict__ sdst, int N)
{
    int w = blockIdx.x * 4 + (threadIdx.x >> 6);
    int i = w >> 3, k = w & 7, l = threadIdx.x & 63;
    if (i >= N) return;
    float v = bf2f(h_all[(size_t)i * 512 + k * 64 + l]);
    float s1 = v * a[k * 128 + l];
    float s2 = v * a[k * 128 + 64 + l];
#pragma unroll
    for (int o = 32; o; o >>= 1) { s1 += __shfl_xor(s1, o); s2 += __shfl_xor(s2, o); }
    if (l == 0) { ssrc[i * 8 + k] = s1; sdst[i * 8 + k] = s2; }
}

// ---------------- CSR build ----------------
__global__ __launch_bounds__(256) void hist(const int* __restrict__ ei, int* __restrict__ cnt, int E) {
    int e = blockIdx.x * 256 + threadIdx.x;
    if (e < E) atomicAdd(&cnt[ei[e]], 1);
}

__global__ __launch_bounds__(256) void scan_partial(const int* __restrict__ cnt, int* __restrict__ bsum, int N) {
    int idx = blockIdx.x * 256 + threadIdx.x;
    int v = (idx < N) ? cnt[idx] : 0;
#pragma unroll
    for (int o = 32; o; o >>= 1) v += __shfl_xor(v, o);
    __shared__ int ws[4];
    if ((threadIdx.x & 63) == 0) ws[threadIdx.x >> 6] = v;
    __syncthreads();
    if (threadIdx.x == 0) bsum[blockIdx.x] = ws[0] + ws[1] + ws[2] + ws[3];
}

__global__ __launch_bounds__(512) void scan_block(int* __restrict__ bsum, int nb) {
    __shared__ int s[512];
    int t = threadIdx.x;
    int v = (t < nb) ? bsum[t] : 0;
    s[t] = v;
    __syncthreads();
    for (int o = 1; o < 512; o <<= 1) {
        int u = (t >= o) ? s[t - o] : 0;
        __syncthreads();
        s[t] += u;
        __syncthreads();
    }
    if (t < nb) bsum[t] = s[t] - v;  // exclusive
}

__global__ __launch_bounds__(256) void scan_final(
    const int* __restrict__ cnt, const int* __restrict__ bsum,
    int* __restrict__ row_ptr, int N, int E)
{
    int b = blockIdx.x, t = threadIdx.x;
    int idx = b * 256 + t;
    int v = (idx < N) ? cnt[idx] : 0;
    __shared__ int s[256];
    s[t] = v;
    __syncthreads();
    for (int o = 1; o < 256; o <<= 1) {
        int u = (t >= o) ? s[t - o] : 0;
        __syncthreads();
        s[t] += u;
        __syncthreads();
    }
    if (idx < N) row_ptr[idx] = bsum[b] + s[t] - v;
    if (idx == 0) row_ptr[N] = E;
}

// fill CSR + precompute all 8 per-head edge scores (once per edge)
__global__ __launch_bounds__(256) void fill_csr(
    const int* __restrict__ ei, const int* __restrict__ row_ptr,
    int* __restrict__ cur, int* __restrict__ col_idx, int* __restrict__ srow,
    const float* __restrict__ ssrc, const float* __restrict__ sdst,
    float* __restrict__ ew1, int E)
{
    int e = blockIdx.x * 256 + threadIdx.x;
    if (e >= E) return;
    int s = ei[e];
    int d = ei[E + e];
    int p = atomicAdd(&cur[s], 1);
    int slot = row_ptr[s] + p;
    col_idx[slot] = d;
    srow[slot] = s;
    float4 as0 = *(const float4*)(ssrc + s * 8);
    float4 as1 = *(const float4*)(ssrc + s * 8 + 4);
    float4 ad0 = *(const float4*)(sdst + d * 8);
    float4 ad1 = *(const float4*)(sdst + d * 8 + 4);
    float sc[8] = { as0.x + ad0.x, as0.y + ad0.y, as0.z + ad0.z, as0.w + ad0.w,
                    as1.x + ad1.x, as1.y + ad1.y, as1.z + ad1.z, as1.w + ad1.w };
    float ev[8];
#pragma unroll
    for (int h = 0; h < 8; ++h) {
        float v = sc[h];
        float lr = v > 0.f ? v : ALPHA_SLOPE * v;
        ev[h] = __expf(-lr);
    }
    float4* dst = (float4*)(ew1 + (size_t)slot * 8);
    dst[0] = make_float4(ev[0], ev[1], ev[2], ev[3]);
    dst[1] = make_float4(ev[4], ev[5], ev[6], ev[7]);
}

// ---------------- layer-1 edge aggregation + normalize + ELU ----------------
// wave per node; lane owns 8 contiguous cols (head = lane>>3). e via broadcast load.
__global__ __launch_bounds__(256) void ea1(
    const int* __restrict__ row_ptr, const int* __restrict__ col_idx,
    const ushort* __restrict__ h_all, const float* __restrict__ ew1,
    ushort* __restrict__ x1)
{
    int w = blockIdx.x * 4 + (threadIdx.x >> 6);   // node
    int l = threadIdx.x & 63;
    int hl = l >> 3;
    int start = row_ptr[w], end = row_ptr[w + 1];
    float acc[8] = {};
    float re = 0.f;
    for (int j = start; j < end; ++j) {
        int d = col_idx[j];
        float e = ew1[(size_t)j * 8 + hl];
        short8 hv = *(const short8*)(h_all + (size_t)d * 512 + l * 8);
        re += e;
#pragma unroll
        for (int q = 0; q < 8; ++q)
            acc[q] = fmaf(e, bf2f((ushort)hv[q]), acc[q]);
    }
    float inv = 1.f / (re + EPS_F);
    short8 o;
#pragma unroll
    for (int q = 0; q < 8; ++q) {
        float p = acc[q] * inv;
        p = p > 0.f ? p : expm1f(p);
        o[q] = (short)f2bf(p);
    }
    *(short8*)(x1 + (size_t)w * 512 + l * 8) = o;
}

// ---------------- layer-2 scores ----------------
__global__ __launch_bounds__(256) void sk2(
    const ushort* __restrict__ h2p, const float* __restrict__ aout,
    float* __restrict__ s2src, float* __restrict__ s2dst, int N)
{
    int w = blockIdx.x * 4 + (threadIdx.x >> 6);
    if (w >= N) return;
    int l = threadIdx.x & 63;
    float s1 = 0.f, s2 = 0.f;
    for (int c = l; c < 97; c += 64) {
        float v = bf2f(h2p[(size_t)w * 128 + c]);
        s1 = fmaf(v, aout[c], s1);
        s2 = fmaf(v, aout[97 + c], s2);
    }
#pragma unroll
    for (int o = 32; o; o >>= 1) { s1 += __shfl_xor(s1, o); s2 += __shfl_xor(s2, o); }
    if (l == 0) { s2src[w] = s1; s2dst[w] = s2; }
}

// layer-2 edge scores
__global__ __launch_bounds__(256) void ew2k(
    const int* __restrict__ srow, const int* __restrict__ col_idx,
    const float* __restrict__ s2src, const float* __restrict__ s2dst,
    float* __restrict__ ew2, int E)
{
    int j = blockIdx.x * 256 + threadIdx.x;
    if (j < E) {
        float s = s2src[srow[j]] + s2dst[col_idx[j]];
        float lr = s > 0.f ? s : ALPHA_SLOPE * s;
        ew2[j] = __expf(-lr);
    }
}

// ---------------- layer-2 aggregation + ELU + log_softmax (f32 out) ----------------
// wave per node; lane owns cols 2l, 2l+1.
__global__ __launch_bounds__(256) void ea2(
    const int* __restrict__ row_ptr, const int* __restrict__ col_idx,
    const ushort* __restrict__ h2p, const float* __restrict__ ew2,
    float* __restrict__ out)
{
    int w = blockIdx.x * 4 + (threadIdx.x >> 6);
    int l = threadIdx.x & 63;
    int start = row_ptr[w], end = row_ptr[w + 1];
    float a0 = 0.f, a1 = 0.f, re = 0.f;
    for (int j = start; j < end; ++j) {
        int d = col_idx[j];
        float e = ew2[j];
        u32 hv = *(const u32*)(h2p + (size_t)d * 128 + 2 * l);
        re += e;
        a0 = fmaf(e, bf2f((ushort)(hv & 0xffffu)), a0);
        a1 = fmaf(e, bf2f((ushort)(hv >> 16)), a1);
    }
    float inv = 1.f / (re + EPS_F);
    float v0 = a0 * inv, v1 = a1 * inv;
    v0 = v0 > 0.f ? v0 : expm1f(v0);
    v1 = v1 > 0.f ? v1 : expm1f(v1);
    int c0 = 2 * l, c1 = 2 * l + 1;
    bool val0 = c0 < 97, val1 = c1 < 97;
    float m = fmaxf(val0 ? v0 : -1e30f, val1 ? v1 : -1e30f);
#pragma unroll
    for (int o = 32; o; o >>= 1) m = fmaxf(m, __shfl_xor(m, o));
    float ex = (val0 ? __expf(v0 - m) : 0.f) + (val1 ? __expf(v1 - m) : 0.f);
#pragma unroll
    for (int o = 32; o; o >>= 1) ex += __shfl_xor(ex, o);
    float lt = m + logf(ex);
    if (val0) out[(size_t)w * 97 + c0] = v0 - lt;
    if (val1) out[(size_t)w * 97 + c1] = v1 - lt;
}

extern "C" void kernel_launch(void* const* d_in, const int* in_sizes, int n_in,
                              void* d_out, int out_size, void* d_ws, size_t ws_size,
                              hipStream_t stream)
{
    const float* feat = (const float*)d_in[0];   // [N,256] f32
    const float* W    = (const float*)d_in[1];   // [8,256,64] f32
    const float* a    = (const float*)d_in[2];   // [8,128] f32
    const float* Wout = (const float*)d_in[3];   // [512,97] f32
    const float* aout = (const float*)d_in[4];   // [194] f32
    const int*   ei   = (const int*)d_in[5];     // [2,E] int32
    float* out = (float*)d_out;                  // [N,97] f32

    const int N = N_NODES, E = N_EDGES;
    const int NB = (N + 255) / 256;  // 391

    // workspace layout with lifetime aliasing
    char* base = (char*)d_ws;
    ushort* h_all = (ushort*)(base);                 // 102,400,000 B  [gemm1 .. ea1]
    ushort* x1    = (ushort*)(base + 102400000);     // 102,400,000 B  [ea1 .. gemm2]
    ushort* featb = (ushort*)(base + 204800000);     // 51,200,000 B   [conv .. gemm1]
    float*  ew1   = (float*)(base + 204800000);      // 51,200,000 B   [fill_csr .. ea1] (aliases featb)
    ushort* h2p   = (ushort*)(base + 204800000);     // 25,600,000 B   [gemm2 .. ea2]    (aliases ew1)
    char* tail = base + 256000000;
    float* ssrc    = (float*)(tail + 0);             // 3,200,000
    float* sdst    = (float*)(tail + 3200000);       // 3,200,000
    float* s2src   = (float*)(tail + 6400000);       // 400,000
    float* s2dst   = (float*)(tail + 6800000);       // 400,000
    int*   row_ptr = (int*)(tail + 7200000);         // 400,128
    int*   cnt     = (int*)(tail + 7600128);         // 400,000
    int*   col_idx = (int*)(tail + 8000128);         // 6,400,000
    int*   bsum    = (int*)(tail + 14400128);        // 1,792
    ushort* Bp1    = (ushort*)(tail + 14401920);     // 262,144
    ushort* Bp2    = (ushort*)(tail + 14664064);     // 131,072
    int*   srow    = (int*)(tail + 14795136);        // 6,400,000
    float* ew2     = (float*)(tail + 21195136);      // 6,400,000  (ends at tail+27,595,136)

    hipMemsetAsync(cnt, 0, (size_t)N * 4, stream);
    conv_feat<<<(N * 256 / 4 + 255) / 256, 256, 0, stream>>>(feat, featb, N * 256 / 4);
    pretranspose<<<512, 256, 0, stream>>>(W, Wout, Bp1, Bp2);

    // layer 1 projections + scores
    gemm_mfma<<<dim3(782, 4), 256, 0, stream>>>(featb, Bp1, h_all, N, 256, 512);
    sk1<<<(N * 8 + 3) / 4, 256, 0, stream>>>(h_all, a, ssrc, sdst, N);

    // CSR + per-edge head scores
    hist<<<(E + 255) / 256, 256, 0, stream>>>(ei, cnt, E);
    scan_partial<<<NB, 256, 0, stream>>>(cnt, bsum, N);
    scan_block<<<1, 512, 0, stream>>>(bsum, NB);
    scan_final<<<NB, 256, 0, stream>>>(cnt, bsum, row_ptr, N, E);
    hipMemsetAsync(cnt, 0, (size_t)N * 4, stream);
    fill_csr<<<(E + 255) / 256, 256, 0, stream>>>(ei, row_ptr, cnt, col_idx, srow, ssrc, sdst, ew1, E);

    // layer 1 aggregation (wave per node)
    ea1<<<N / 4, 256, 0, stream>>>(row_ptr, col_idx, h_all, ew1, x1);

    // layer 2
    gemm_mfma<<<dim3(782, 1), 256, 0, stream>>>(x1, Bp2, h2p, N, 512, 128);
    sk2<<<(N + 3) / 4, 256, 0, stream>>>(h2p, aout, s2src, s2dst, N);
    ew2k<<<(E + 255) / 256, 256, 0, stream>>>(srow, col_idx, s2src, s2dst, ew2, E);
    ea2<<<N / 4, 256, 0, stream>>>(row_ptr, col_idx, h2p, ew2, out);
}

// Round 4
// 920.674 us; speedup vs baseline: 1.1111x; 1.1111x over previous
//
#include <hip/hip_runtime.h>
#include <hip/hip_bf16.h>
#include <stdint.h>

typedef __attribute__((ext_vector_type(8))) short short8;
typedef __attribute__((ext_vector_type(4))) float floatx4;
typedef uint32_t u32;

#define N_NODES 100000
#define N_EDGES 1600000
#define ALPHA_SLOPE 0.2f
#define EPS_F 1e-16f

static __device__ __forceinline__ float bf2f(ushort h) {
    u32 u = ((u32)h) << 16;
    return __builtin_bit_cast(float, u);
}
static __device__ __forceinline__ ushort f2bf(float f) {
    u32 u = __builtin_bit_cast(u32, f);
    u32 r = (u + 0x7fffu + ((u >> 16) & 1u)) >> 16;
    return (ushort)r;
}

// ---------------- convert features f32 -> bf16 (vectorized) ----------------
__global__ __launch_bounds__(256) void conv_feat(
    const float* __restrict__ in, ushort* __restrict__ out, int n4)
{
    int i = blockIdx.x * 256 + threadIdx.x;
    if (i < n4) {
        float4 v = ((const float4*)in)[i];
        ushort4 o;
        o.x = f2bf(v.x); o.y = f2bf(v.y); o.z = f2bf(v.z); o.w = f2bf(v.w);
        ((ushort4*)out)[i] = o;
    }
}

// ---------------- pretranspose weights + build per-column a vectors ----------------
__global__ __launch_bounds__(256) void pretranspose(
    const float* __restrict__ W, const float* __restrict__ Wout,
    const float* __restrict__ a, const float* __restrict__ aout,
    ushort* __restrict__ Bp1, ushort* __restrict__ Bp2,
    float* __restrict__ acol1, float* __restrict__ acol2)
{
    int idx = blockIdx.x * 256 + threadIdx.x;
    if (idx < 256 * 512) {  // Bp1: K=256, N=512
        int k = idx >> 9, n = idx & 511;
        int head = n >> 6, c = n & 63;
        Bp1[((size_t)(k >> 3) * 512 + n) * 8 + (k & 7)] = f2bf(W[head * 16384 + k * 64 + c]);
    }
    if (idx < 512 * 128) {  // Bp2: K=512, N=97 padded to 128
        int k = idx >> 7, n = idx & 127;
        ushort v = (n < 97) ? f2bf(Wout[k * 97 + n]) : (ushort)0;
        Bp2[((size_t)(k >> 3) * 128 + n) * 8 + (k & 7)] = v;
    }
    if (idx < 512) {        // acol1[col][2]
        int head = idx >> 6, c = idx & 63;
        acol1[idx * 2]     = a[head * 128 + c];
        acol1[idx * 2 + 1] = a[head * 128 + 64 + c];
    }
    if (idx < 128) {        // acol2[col][2]
        acol2[idx * 2]     = (idx < 97) ? aout[idx] : 0.f;
        acol2[idx * 2 + 1] = (idx < 97) ? aout[97 + idx] : 0.f;
    }
}

// ---------------- MFMA GEMM + fused score epilogue ----------------
// C[M,NP] = A @ B; additionally spair[(row*(NP/64)+g)*2 + {0,1}] += sum_{col in g} C*acol{1,2}
__global__ __launch_bounds__(256) void gemm_mfma(
    const ushort* __restrict__ A, const ushort* __restrict__ Bp,
    ushort* __restrict__ C, const float* __restrict__ acol,
    float* __restrict__ spair, int M, int K, int NP)
{
    __shared__ __align__(16) ushort Ald[4 * 128 * 8];  // [kq][r][j], 8 KB
    const int tid = threadIdx.x;
    const int lane = tid & 63;
    const int wave = tid >> 6;
    const int wr = wave >> 1, wc = wave & 1;
    const int row0 = blockIdx.x * 128;
    const int col0 = blockIdx.y * 128;
    const int quad = lane >> 4;
    const int l16 = lane & 15;

    floatx4 acc[4][4] = {};

    for (int k0 = 0; k0 < K; k0 += 32) {
        __syncthreads();
#pragma unroll
        for (int i = 0; i < 2; ++i) {
            int q = i * 256 + tid;          // 512 chunks of 16B
            int r = q >> 2, kq = q & 3;
            int row = row0 + r;
            if (row >= M) row = M - 1;      // clamp: garbage rows never stored
            const uint4* src = (const uint4*)(A + (size_t)row * K + k0 + kq * 8);
            *(uint4*)(&Ald[((kq * 128 + r) * 8)]) = *src;
        }
        __syncthreads();

        short8 bfrag[4];
        int kqg = (k0 >> 3) + quad;
#pragma unroll
        for (int nt = 0; nt < 4; ++nt) {
            int col = col0 + wc * 64 + nt * 16 + l16;
            bfrag[nt] = *(const short8*)(Bp + ((size_t)kqg * NP + col) * 8);
        }
#pragma unroll
        for (int mt = 0; mt < 4; ++mt) {
            int r = wr * 64 + mt * 16 + l16;
            short8 afrag = *(const short8*)(&Ald[(quad * 128 + r) * 8]);
#pragma unroll
            for (int nt = 0; nt < 4; ++nt) {
                acc[mt][nt] = __builtin_amdgcn_mfma_f32_16x16x32_bf16(afrag, bfrag[nt], acc[mt][nt], 0, 0, 0);
            }
        }
    }

    // C store
#pragma unroll
    for (int mt = 0; mt < 4; ++mt) {
#pragma unroll
        for (int rr = 0; rr < 4; ++rr) {
            int row = row0 + wr * 64 + mt * 16 + quad * 4 + rr;
            if (row < M) {
#pragma unroll
                for (int nt = 0; nt < 4; ++nt) {
                    int col = col0 + wc * 64 + nt * 16 + l16;
                    C[(size_t)row * NP + col] = f2bf(acc[mt][nt][rr]);
                }
            }
        }
    }

    // fused score epilogue: this wave covers one 64-col group g
    float av1[4], av2[4];
#pragma unroll
    for (int nt = 0; nt < 4; ++nt) {
        int col = col0 + wc * 64 + nt * 16 + l16;
        av1[nt] = acol[col * 2];
        av2[nt] = acol[col * 2 + 1];
    }
    int g = (col0 + wc * 64) >> 6;
    int ng = NP >> 6;
#pragma unroll
    for (int mt = 0; mt < 4; ++mt) {
#pragma unroll
        for (int rr = 0; rr < 4; ++rr) {
            float p1 = 0.f, p2 = 0.f;
#pragma unroll
            for (int nt = 0; nt < 4; ++nt) {
                p1 = fmaf(acc[mt][nt][rr], av1[nt], p1);
                p2 = fmaf(acc[mt][nt][rr], av2[nt], p2);
            }
#pragma unroll
            for (int o = 1; o < 16; o <<= 1) {
                p1 += __shfl_xor(p1, o);
                p2 += __shfl_xor(p2, o);
            }
            int row = row0 + wr * 64 + mt * 16 + quad * 4 + rr;
            if (l16 == 0 && row < M) {
                atomicAdd(&spair[((size_t)row * ng + g) * 2], p1);
                atomicAdd(&spair[((size_t)row * ng + g) * 2 + 1], p2);
            }
        }
    }
}

// ---------------- CSR build ----------------
__global__ __launch_bounds__(256) void hist(const int* __restrict__ ei, int* __restrict__ cnt, int E) {
    int e = blockIdx.x * 256 + threadIdx.x;
    if (e < E) atomicAdd(&cnt[ei[e]], 1);
}

__global__ __launch_bounds__(256) void scan_partial(const int* __restrict__ cnt, int* __restrict__ bsum, int N) {
    int idx = blockIdx.x * 256 + threadIdx.x;
    int v = (idx < N) ? cnt[idx] : 0;
#pragma unroll
    for (int o = 32; o; o >>= 1) v += __shfl_xor(v, o);
    __shared__ int ws[4];
    if ((threadIdx.x & 63) == 0) ws[threadIdx.x >> 6] = v;
    __syncthreads();
    if (threadIdx.x == 0) bsum[blockIdx.x] = ws[0] + ws[1] + ws[2] + ws[3];
}

__global__ __launch_bounds__(512) void scan_block(int* __restrict__ bsum, int nb) {
    __shared__ int s[512];
    int t = threadIdx.x;
    int v = (t < nb) ? bsum[t] : 0;
    s[t] = v;
    __syncthreads();
    for (int o = 1; o < 512; o <<= 1) {
        int u = (t >= o) ? s[t - o] : 0;
        __syncthreads();
        s[t] += u;
        __syncthreads();
    }
    if (t < nb) bsum[t] = s[t] - v;  // exclusive
}

__global__ __launch_bounds__(256) void scan_final(
    const int* __restrict__ cnt, const int* __restrict__ bsum,
    int* __restrict__ row_ptr, int N, int E)
{
    int b = blockIdx.x, t = threadIdx.x;
    int idx = b * 256 + t;
    int v = (idx < N) ? cnt[idx] : 0;
    __shared__ int s[256];
    s[t] = v;
    __syncthreads();
    for (int o = 1; o < 256; o <<= 1) {
        int u = (t >= o) ? s[t - o] : 0;
        __syncthreads();
        s[t] += u;
        __syncthreads();
    }
    if (idx < N) row_ptr[idx] = bsum[b] + s[t] - v;
    if (idx == 0) row_ptr[N] = E;
}

// fill CSR + precompute all 8 per-head edge scores (once per edge)
// spair1 layout: [N][8][2] (src-score, dst-score per head)
__global__ __launch_bounds__(256) void fill_csr(
    const int* __restrict__ ei, const int* __restrict__ row_ptr,
    int* __restrict__ cur, int* __restrict__ col_idx, int* __restrict__ srow,
    const float* __restrict__ spair1, float* __restrict__ ew1, int E)
{
    int e = blockIdx.x * 256 + threadIdx.x;
    if (e >= E) return;
    int s = ei[e];
    int d = ei[E + e];
    int p = atomicAdd(&cur[s], 1);
    int slot = row_ptr[s] + p;
    col_idx[slot] = d;
    srow[slot] = s;
    const float4* qs = (const float4*)(spair1 + (size_t)s * 16);
    const float4* qd = (const float4*)(spair1 + (size_t)d * 16);
    float ev[8];
#pragma unroll
    for (int h4 = 0; h4 < 4; ++h4) {
        float4 vs = qs[h4];
        float4 vd = qd[h4];
        float v0 = vs.x + vd.y;   // head 2*h4:   src.x + dst.y
        float v1 = vs.z + vd.w;   // head 2*h4+1
        float l0 = v0 > 0.f ? v0 : ALPHA_SLOPE * v0;
        float l1 = v1 > 0.f ? v1 : ALPHA_SLOPE * v1;
        ev[2 * h4] = __expf(-l0);
        ev[2 * h4 + 1] = __expf(-l1);
    }
    float4* dst = (float4*)(ew1 + (size_t)slot * 8);
    dst[0] = make_float4(ev[0], ev[1], ev[2], ev[3]);
    dst[1] = make_float4(ev[4], ev[5], ev[6], ev[7]);
}

// ---------------- layer-1 edge aggregation + normalize + ELU (wave/node, 4x unroll) ----------------
__global__ __launch_bounds__(256) void ea1(
    const int* __restrict__ row_ptr, const int* __restrict__ col_idx,
    const ushort* __restrict__ h_all, const float* __restrict__ ew1,
    ushort* __restrict__ x1)
{
    int w = blockIdx.x * 4 + (threadIdx.x >> 6);   // node
    int l = threadIdx.x & 63;
    int hl = l >> 3;
    int start = row_ptr[w], end = row_ptr[w + 1];
    float acc[8] = {};
    float re = 0.f;
    int j = start;
    for (; j + 4 <= end; j += 4) {
        int d0 = col_idx[j], d1 = col_idx[j + 1], d2 = col_idx[j + 2], d3 = col_idx[j + 3];
        float e0 = ew1[(size_t)j * 8 + hl];
        float e1 = ew1[(size_t)(j + 1) * 8 + hl];
        float e2 = ew1[(size_t)(j + 2) * 8 + hl];
        float e3 = ew1[(size_t)(j + 3) * 8 + hl];
        short8 v0 = *(const short8*)(h_all + (size_t)d0 * 512 + l * 8);
        short8 v1 = *(const short8*)(h_all + (size_t)d1 * 512 + l * 8);
        short8 v2 = *(const short8*)(h_all + (size_t)d2 * 512 + l * 8);
        short8 v3 = *(const short8*)(h_all + (size_t)d3 * 512 + l * 8);
        re += (e0 + e1) + (e2 + e3);
#pragma unroll
        for (int q = 0; q < 8; ++q) {
            float t0 = fmaf(e0, bf2f((ushort)v0[q]), e1 * bf2f((ushort)v1[q]));
            float t1 = fmaf(e2, bf2f((ushort)v2[q]), e3 * bf2f((ushort)v3[q]));
            acc[q] += t0 + t1;
        }
    }
    for (; j < end; ++j) {
        int d = col_idx[j];
        float e = ew1[(size_t)j * 8 + hl];
        short8 hv = *(const short8*)(h_all + (size_t)d * 512 + l * 8);
        re += e;
#pragma unroll
        for (int q = 0; q < 8; ++q)
            acc[q] = fmaf(e, bf2f((ushort)hv[q]), acc[q]);
    }
    float inv = 1.f / (re + EPS_F);
    short8 o;
#pragma unroll
    for (int q = 0; q < 8; ++q) {
        float p = acc[q] * inv;
        p = p > 0.f ? p : expm1f(p);
        o[q] = (short)f2bf(p);
    }
    *(short8*)(x1 + (size_t)w * 512 + l * 8) = o;
}

// layer-2 edge scores; spair2 layout [N][2 groups][2]
__global__ __launch_bounds__(256) void ew2k(
    const int* __restrict__ srow, const int* __restrict__ col_idx,
    const float* __restrict__ spair2, float* __restrict__ ew2, int E)
{
    int j = blockIdx.x * 256 + threadIdx.x;
    if (j < E) {
        float4 vs = *(const float4*)(spair2 + (size_t)srow[j] * 4);
        float4 vd = *(const float4*)(spair2 + (size_t)col_idx[j] * 4);
        float s = (vs.x + vs.z) + (vd.y + vd.w);
        float lr = s > 0.f ? s : ALPHA_SLOPE * s;
        ew2[j] = __expf(-lr);
    }
}

// ---------------- layer-2 aggregation + ELU + log_softmax (wave/node, 4x unroll) ----------------
__global__ __launch_bounds__(256) void ea2(
    const int* __restrict__ row_ptr, const int* __restrict__ col_idx,
    const ushort* __restrict__ h2p, const float* __restrict__ ew2,
    float* __restrict__ out)
{
    int w = blockIdx.x * 4 + (threadIdx.x >> 6);
    int l = threadIdx.x & 63;
    int start = row_ptr[w], end = row_ptr[w + 1];
    float a0 = 0.f, a1 = 0.f, re = 0.f;
    int j = start;
    for (; j + 4 <= end; j += 4) {
        int d0 = col_idx[j], d1 = col_idx[j + 1], d2 = col_idx[j + 2], d3 = col_idx[j + 3];
        float e0 = ew2[j], e1 = ew2[j + 1], e2 = ew2[j + 2], e3 = ew2[j + 3];
        u32 h0 = *(const u32*)(h2p + (size_t)d0 * 128 + 2 * l);
        u32 h1 = *(const u32*)(h2p + (size_t)d1 * 128 + 2 * l);
        u32 h2 = *(const u32*)(h2p + (size_t)d2 * 128 + 2 * l);
        u32 h3 = *(const u32*)(h2p + (size_t)d3 * 128 + 2 * l);
        re += (e0 + e1) + (e2 + e3);
        a0 += fmaf(e0, bf2f((ushort)(h0 & 0xffffu)), e1 * bf2f((ushort)(h1 & 0xffffu)))
            + fmaf(e2, bf2f((ushort)(h2 & 0xffffu)), e3 * bf2f((ushort)(h3 & 0xffffu)));
        a1 += fmaf(e0, bf2f((ushort)(h0 >> 16)), e1 * bf2f((ushort)(h1 >> 16)))
            + fmaf(e2, bf2f((ushort)(h2 >> 16)), e3 * bf2f((ushort)(h3 >> 16)));
    }
    for (; j < end; ++j) {
        int d = col_idx[j];
        float e = ew2[j];
        u32 hv = *(const u32*)(h2p + (size_t)d * 128 + 2 * l);
        re += e;
        a0 = fmaf(e, bf2f((ushort)(hv & 0xffffu)), a0);
        a1 = fmaf(e, bf2f((ushort)(hv >> 16)), a1);
    }
    float inv = 1.f / (re + EPS_F);
    float v0 = a0 * inv, v1 = a1 * inv;
    v0 = v0 > 0.f ? v0 : expm1f(v0);
    v1 = v1 > 0.f ? v1 : expm1f(v1);
    int c0 = 2 * l, c1 = 2 * l + 1;
    bool val0 = c0 < 97, val1 = c1 < 97;
    float m = fmaxf(val0 ? v0 : -1e30f, val1 ? v1 : -1e30f);
#pragma unroll
    for (int o = 32; o; o >>= 1) m = fmaxf(m, __shfl_xor(m, o));
    float ex = (val0 ? __expf(v0 - m) : 0.f) + (val1 ? __expf(v1 - m) : 0.f);
#pragma unroll
    for (int o = 32; o; o >>= 1) ex += __shfl_xor(ex, o);
    float lt = m + logf(ex);
    if (val0) out[(size_t)w * 97 + c0] = v0 - lt;
    if (val1) out[(size_t)w * 97 + c1] = v1 - lt;
}

extern "C" void kernel_launch(void* const* d_in, const int* in_sizes, int n_in,
                              void* d_out, int out_size, void* d_ws, size_t ws_size,
                              hipStream_t stream)
{
    const float* feat = (const float*)d_in[0];   // [N,256] f32
    const float* W    = (const float*)d_in[1];   // [8,256,64] f32
    const float* a    = (const float*)d_in[2];   // [8,128] f32
    const float* Wout = (const float*)d_in[3];   // [512,97] f32
    const float* aout = (const float*)d_in[4];   // [194] f32
    const int*   ei   = (const int*)d_in[5];     // [2,E] int32
    float* out = (float*)d_out;                  // [N,97] f32

    const int N = N_NODES, E = N_EDGES;
    const int NB = (N + 255) / 256;  // 391

    // workspace layout with lifetime aliasing
    char* base = (char*)d_ws;
    ushort* h_all = (ushort*)(base);                 // 102,400,000 B  [gemm1 .. ea1]
    ushort* x1    = (ushort*)(base + 102400000);     // 102,400,000 B  [ea1 .. gemm2]
    ushort* featb = (ushort*)(base + 204800000);     // 51,200,000 B   [conv .. gemm1]
    float*  ew1   = (float*)(base + 204800000);      // 51,200,000 B   [fill_csr .. ea1] (aliases featb)
    ushort* h2p   = (ushort*)(base + 204800000);     // 25,600,000 B   [gemm2 .. ea2]    (aliases ew1)
    char* tail = base + 256000000;
    float* spair1  = (float*)(tail + 0);             // 6,400,000  [N][8][2]
    float* spair2  = (float*)(tail + 6400000);       // 1,600,000  [N][2][2]
    int*   row_ptr = (int*)(tail + 8000000);         // 400,128
    int*   cnt     = (int*)(tail + 8400128);         // 400,000
    int*   col_idx = (int*)(tail + 8800128);         // 6,400,000
    int*   bsum    = (int*)(tail + 15200128);        // 1,792
    ushort* Bp1    = (ushort*)(tail + 15201920);     // 262,144
    ushort* Bp2    = (ushort*)(tail + 15464064);     // 131,072
    float* acol1   = (float*)(tail + 15595136);      // 4,096
    float* acol2   = (float*)(tail + 15599232);      // 1,024
    int*   srow    = (int*)(tail + 15600256);        // 6,400,000
    float* ew2     = (float*)(tail + 22000256);      // 6,400,000  (ends at tail+28,400,256)

    hipMemsetAsync(cnt, 0, (size_t)N * 4, stream);
    hipMemsetAsync(spair1, 0, (size_t)N * 16 * 4, stream);
    hipMemsetAsync(spair2, 0, (size_t)N * 4 * 4, stream);
    conv_feat<<<(N * 256 / 4 + 255) / 256, 256, 0, stream>>>(feat, featb, N * 256 / 4);
    pretranspose<<<512, 256, 0, stream>>>(W, Wout, a, aout, Bp1, Bp2, acol1, acol2);

    // layer 1 projection (+ fused score reduction)
    gemm_mfma<<<dim3(782, 4), 256, 0, stream>>>(featb, Bp1, h_all, acol1, spair1, N, 256, 512);

    // CSR + per-edge head scores
    hist<<<(E + 255) / 256, 256, 0, stream>>>(ei, cnt, E);
    scan_partial<<<NB, 256, 0, stream>>>(cnt, bsum, N);
    scan_block<<<1, 512, 0, stream>>>(bsum, NB);
    scan_final<<<NB, 256, 0, stream>>>(cnt, bsum, row_ptr, N, E);
    hipMemsetAsync(cnt, 0, (size_t)N * 4, stream);
    fill_csr<<<(E + 255) / 256, 256, 0, stream>>>(ei, row_ptr, cnt, col_idx, srow, spair1, ew1, E);

    // layer 1 aggregation (wave per node)
    ea1<<<N / 4, 256, 0, stream>>>(row_ptr, col_idx, h_all, ew1, x1);

    // layer 2
    gemm_mfma<<<dim3(782, 1), 256, 0, stream>>>(x1, Bp2, h2p, acol2, spair2, N, 512, 128);
    ew2k<<<(E + 255) / 256, 256, 0, stream>>>(srow, col_idx, spair2, ew2, E);
    ea2<<<N / 4, 256, 0, stream>>>(row_ptr, col_idx, h2p, ew2, out);
}

// Round 5
// 865.542 us; speedup vs baseline: 1.1818x; 1.0637x over previous
//
#include <hip/hip_runtime.h>
#include <hip/hip_bf16.h>
#include <stdint.h>

typedef __attribute__((ext_vector_type(8))) short short8;
typedef __attribute__((ext_vector_type(4))) float floatx4;
typedef uint32_t u32;

#define N_NODES 100000
#define N_EDGES 1600000
#define ALPHA_SLOPE 0.2f
#define EPS_F 1e-16f

static __device__ __forceinline__ float bf2f(ushort h) {
    u32 u = ((u32)h) << 16;
    return __builtin_bit_cast(float, u);
}
static __device__ __forceinline__ ushort f2bf(float f) {
    u32 u = __builtin_bit_cast(u32, f);
    u32 r = (u + 0x7fffu + ((u >> 16) & 1u)) >> 16;
    return (ushort)r;
}
static __device__ __forceinline__ float edge_e(float s) {
    float lr = s > 0.f ? s : ALPHA_SLOPE * s;
    return __expf(-lr);
}

// ---------------- convert features f32 -> bf16 (vectorized) ----------------
__global__ __launch_bounds__(256) void conv_feat(
    const float* __restrict__ in, ushort* __restrict__ out, int n4)
{
    int i = blockIdx.x * 256 + threadIdx.x;
    if (i < n4) {
        float4 v = ((const float4*)in)[i];
        ushort4 o;
        o.x = f2bf(v.x); o.y = f2bf(v.y); o.z = f2bf(v.z); o.w = f2bf(v.w);
        ((ushort4*)out)[i] = o;
    }
}

// ---------------- pretranspose weights + build per-column a vectors ----------------
__global__ __launch_bounds__(256) void pretranspose(
    const float* __restrict__ W, const float* __restrict__ Wout,
    const float* __restrict__ a, const float* __restrict__ aout,
    ushort* __restrict__ Bp1, ushort* __restrict__ Bp2,
    float* __restrict__ acol1, float* __restrict__ acol2)
{
    int idx = blockIdx.x * 256 + threadIdx.x;
    if (idx < 256 * 512) {  // Bp1: K=256, N=512
        int k = idx >> 9, n = idx & 511;
        int head = n >> 6, c = n & 63;
        Bp1[((size_t)(k >> 3) * 512 + n) * 8 + (k & 7)] = f2bf(W[head * 16384 + k * 64 + c]);
    }
    if (idx < 512 * 128) {  // Bp2: K=512, N=97 padded to 128
        int k = idx >> 7, n = idx & 127;
        ushort v = (n < 97) ? f2bf(Wout[k * 97 + n]) : (ushort)0;
        Bp2[((size_t)(k >> 3) * 128 + n) * 8 + (k & 7)] = v;
    }
    if (idx < 512) {        // acol1[col][2]
        int head = idx >> 6, c = idx & 63;
        acol1[idx * 2]     = a[head * 128 + c];
        acol1[idx * 2 + 1] = a[head * 128 + 64 + c];
    }
    if (idx < 128) {        // acol2[col][2]
        acol2[idx * 2]     = (idx < 97) ? aout[idx] : 0.f;
        acol2[idx * 2 + 1] = (idx < 97) ? aout[97 + idx] : 0.f;
    }
}

// ---------------- MFMA GEMM + fused score epilogue ----------------
// C[M,NP] = A @ B; ssrc_arr[row*sstride + g'] += sum_col C*acol[.,0], sdst_arr likewise.
// sstride=8 (layer1: g'=group=head), sstride=1 (layer2: both groups sum into one slot).
__global__ __launch_bounds__(256) void gemm_mfma(
    const ushort* __restrict__ A, const ushort* __restrict__ Bp,
    ushort* __restrict__ C, const float* __restrict__ acol,
    float* __restrict__ ssrc_arr, float* __restrict__ sdst_arr,
    int sstride, int M, int K, int NP)
{
    __shared__ __align__(16) ushort Ald[4 * 128 * 8];  // [kq][r][j], 8 KB
    const int tid = threadIdx.x;
    const int lane = tid & 63;
    const int wave = tid >> 6;
    const int wr = wave >> 1, wc = wave & 1;
    const int row0 = blockIdx.x * 128;
    const int col0 = blockIdx.y * 128;
    const int quad = lane >> 4;
    const int l16 = lane & 15;

    floatx4 acc[4][4] = {};

    for (int k0 = 0; k0 < K; k0 += 32) {
        __syncthreads();
#pragma unroll
        for (int i = 0; i < 2; ++i) {
            int q = i * 256 + tid;          // 512 chunks of 16B
            int r = q >> 2, kq = q & 3;
            int row = row0 + r;
            if (row >= M) row = M - 1;      // clamp: garbage rows never stored
            const uint4* src = (const uint4*)(A + (size_t)row * K + k0 + kq * 8);
            *(uint4*)(&Ald[((kq * 128 + r) * 8)]) = *src;
        }
        __syncthreads();

        short8 bfrag[4];
        int kqg = (k0 >> 3) + quad;
#pragma unroll
        for (int nt = 0; nt < 4; ++nt) {
            int col = col0 + wc * 64 + nt * 16 + l16;
            bfrag[nt] = *(const short8*)(Bp + ((size_t)kqg * NP + col) * 8);
        }
#pragma unroll
        for (int mt = 0; mt < 4; ++mt) {
            int r = wr * 64 + mt * 16 + l16;
            short8 afrag = *(const short8*)(&Ald[(quad * 128 + r) * 8]);
#pragma unroll
            for (int nt = 0; nt < 4; ++nt) {
                acc[mt][nt] = __builtin_amdgcn_mfma_f32_16x16x32_bf16(afrag, bfrag[nt], acc[mt][nt], 0, 0, 0);
            }
        }
    }

    // C store
#pragma unroll
    for (int mt = 0; mt < 4; ++mt) {
#pragma unroll
        for (int rr = 0; rr < 4; ++rr) {
            int row = row0 + wr * 64 + mt * 16 + quad * 4 + rr;
            if (row < M) {
#pragma unroll
                for (int nt = 0; nt < 4; ++nt) {
                    int col = col0 + wc * 64 + nt * 16 + l16;
                    C[(size_t)row * NP + col] = f2bf(acc[mt][nt][rr]);
                }
            }
        }
    }

    // fused score epilogue: this wave covers one 64-col group g
    float av1[4], av2[4];
#pragma unroll
    for (int nt = 0; nt < 4; ++nt) {
        int col = col0 + wc * 64 + nt * 16 + l16;
        av1[nt] = acol[col * 2];
        av2[nt] = acol[col * 2 + 1];
    }
    int g = (col0 + wc * 64) >> 6;
    int goff = (sstride > 1) ? g : 0;
#pragma unroll
    for (int mt = 0; mt < 4; ++mt) {
#pragma unroll
        for (int rr = 0; rr < 4; ++rr) {
            float p1 = 0.f, p2 = 0.f;
#pragma unroll
            for (int nt = 0; nt < 4; ++nt) {
                p1 = fmaf(acc[mt][nt][rr], av1[nt], p1);
                p2 = fmaf(acc[mt][nt][rr], av2[nt], p2);
            }
#pragma unroll
            for (int o = 1; o < 16; o <<= 1) {
                p1 += __shfl_xor(p1, o);
                p2 += __shfl_xor(p2, o);
            }
            int row = row0 + wr * 64 + mt * 16 + quad * 4 + rr;
            if (l16 == 0 && row < M) {
                atomicAdd(&ssrc_arr[(size_t)row * sstride + goff], p1);
                atomicAdd(&sdst_arr[(size_t)row * sstride + goff], p2);
            }
        }
    }
}

// ---------------- CSR build ----------------
__global__ __launch_bounds__(256) void hist(const int* __restrict__ ei, int* __restrict__ cnt, int E) {
    int e = blockIdx.x * 256 + threadIdx.x;
    if (e < E) atomicAdd(&cnt[ei[e]], 1);
}

__global__ __launch_bounds__(256) void scan_partial(const int* __restrict__ cnt, int* __restrict__ bsum, int N) {
    int idx = blockIdx.x * 256 + threadIdx.x;
    int v = (idx < N) ? cnt[idx] : 0;
#pragma unroll
    for (int o = 32; o; o >>= 1) v += __shfl_xor(v, o);
    __shared__ int ws[4];
    if ((threadIdx.x & 63) == 0) ws[threadIdx.x >> 6] = v;
    __syncthreads();
    if (threadIdx.x == 0) bsum[blockIdx.x] = ws[0] + ws[1] + ws[2] + ws[3];
}

__global__ __launch_bounds__(512) void scan_block(int* __restrict__ bsum, int nb) {
    __shared__ int s[512];
    int t = threadIdx.x;
    int v = (t < nb) ? bsum[t] : 0;
    s[t] = v;
    __syncthreads();
    for (int o = 1; o < 512; o <<= 1) {
        int u = (t >= o) ? s[t - o] : 0;
        __syncthreads();
        s[t] += u;
        __syncthreads();
    }
    if (t < nb) bsum[t] = s[t] - v;  // exclusive
}

__global__ __launch_bounds__(256) void scan_final(
    const int* __restrict__ cnt, const int* __restrict__ bsum,
    int* __restrict__ row_ptr, int N, int E)
{
    int b = blockIdx.x, t = threadIdx.x;
    int idx = b * 256 + t;
    int v = (idx < N) ? cnt[idx] : 0;
    __shared__ int s[256];
    s[t] = v;
    __syncthreads();
    for (int o = 1; o < 256; o <<= 1) {
        int u = (t >= o) ? s[t - o] : 0;
        __syncthreads();
        s[t] += u;
        __syncthreads();
    }
    if (idx < N) row_ptr[idx] = bsum[b] + s[t] - v;
    if (idx == 0) row_ptr[N] = E;
}

// fill CSR (col_idx + srow only; scores computed inline by consumers)
__global__ __launch_bounds__(256) void fill_csr(
    const int* __restrict__ ei, const int* __restrict__ row_ptr,
    int* __restrict__ cur, int* __restrict__ col_idx, int* __restrict__ srow, int E)
{
    int e = blockIdx.x * 256 + threadIdx.x;
    if (e >= E) return;
    int s = ei[e];
    int d = ei[E + e];
    int p = atomicAdd(&cur[s], 1);
    int slot = row_ptr[s] + p;
    col_idx[slot] = d;
    srow[slot] = s;
}

// ---------------- layer-1 edge aggregation (inline scores) + normalize + ELU ----------------
// wave per node; lane owns 8 contiguous cols (head hl = l>>3); e computed per lane.
__global__ __launch_bounds__(256) void ea1(
    const int* __restrict__ row_ptr, const int* __restrict__ col_idx,
    const ushort* __restrict__ h_all, const float* __restrict__ ssrc1,
    const float* __restrict__ sdst1, ushort* __restrict__ x1)
{
    int w = blockIdx.x * 4 + (threadIdx.x >> 6);   // node
    int l = threadIdx.x & 63;
    int hl = l >> 3;
    int start = row_ptr[w], end = row_ptr[w + 1];
    float si = ssrc1[(size_t)w * 8 + hl];
    float acc[8] = {};
    float re = 0.f;
    int j = start;
    for (; j + 4 <= end; j += 4) {
        int d0 = col_idx[j], d1 = col_idx[j + 1], d2 = col_idx[j + 2], d3 = col_idx[j + 3];
        float e0 = edge_e(si + sdst1[(size_t)d0 * 8 + hl]);
        float e1 = edge_e(si + sdst1[(size_t)d1 * 8 + hl]);
        float e2 = edge_e(si + sdst1[(size_t)d2 * 8 + hl]);
        float e3 = edge_e(si + sdst1[(size_t)d3 * 8 + hl]);
        short8 v0 = *(const short8*)(h_all + (size_t)d0 * 512 + l * 8);
        short8 v1 = *(const short8*)(h_all + (size_t)d1 * 512 + l * 8);
        short8 v2 = *(const short8*)(h_all + (size_t)d2 * 512 + l * 8);
        short8 v3 = *(const short8*)(h_all + (size_t)d3 * 512 + l * 8);
        re += (e0 + e1) + (e2 + e3);
#pragma unroll
        for (int q = 0; q < 8; ++q) {
            float t0 = fmaf(e0, bf2f((ushort)v0[q]), e1 * bf2f((ushort)v1[q]));
            float t1 = fmaf(e2, bf2f((ushort)v2[q]), e3 * bf2f((ushort)v3[q]));
            acc[q] += t0 + t1;
        }
    }
    for (; j < end; ++j) {
        int d = col_idx[j];
        float e = edge_e(si + sdst1[(size_t)d * 8 + hl]);
        short8 hv = *(const short8*)(h_all + (size_t)d * 512 + l * 8);
        re += e;
#pragma unroll
        for (int q = 0; q < 8; ++q)
            acc[q] = fmaf(e, bf2f((ushort)hv[q]), acc[q]);
    }
    float inv = 1.f / (re + EPS_F);
    short8 o;
#pragma unroll
    for (int q = 0; q < 8; ++q) {
        float p = acc[q] * inv;
        p = p > 0.f ? p : expm1f(p);
        o[q] = (short)f2bf(p);
    }
    __builtin_nontemporal_store(o, (short8*)(x1 + (size_t)w * 512 + l * 8));
}

// ---------------- layer-2 aggregation (inline scores) + ELU + log_softmax ----------------
__global__ __launch_bounds__(256) void ea2(
    const int* __restrict__ row_ptr, const int* __restrict__ col_idx,
    const ushort* __restrict__ h2p, const float* __restrict__ s2src,
    const float* __restrict__ s2dst, float* __restrict__ out)
{
    int w = blockIdx.x * 4 + (threadIdx.x >> 6);
    int l = threadIdx.x & 63;
    int start = row_ptr[w], end = row_ptr[w + 1];
    float si = s2src[w];
    float a0 = 0.f, a1 = 0.f, re = 0.f;
    int j = start;
    for (; j + 4 <= end; j += 4) {
        int d0 = col_idx[j], d1 = col_idx[j + 1], d2 = col_idx[j + 2], d3 = col_idx[j + 3];
        float e0 = edge_e(si + s2dst[d0]);
        float e1 = edge_e(si + s2dst[d1]);
        float e2 = edge_e(si + s2dst[d2]);
        float e3 = edge_e(si + s2dst[d3]);
        u32 h0 = *(const u32*)(h2p + (size_t)d0 * 128 + 2 * l);
        u32 h1 = *(const u32*)(h2p + (size_t)d1 * 128 + 2 * l);
        u32 h2 = *(const u32*)(h2p + (size_t)d2 * 128 + 2 * l);
        u32 h3 = *(const u32*)(h2p + (size_t)d3 * 128 + 2 * l);
        re += (e0 + e1) + (e2 + e3);
        a0 += fmaf(e0, bf2f((ushort)(h0 & 0xffffu)), e1 * bf2f((ushort)(h1 & 0xffffu)))
            + fmaf(e2, bf2f((ushort)(h2 & 0xffffu)), e3 * bf2f((ushort)(h3 & 0xffffu)));
        a1 += fmaf(e0, bf2f((ushort)(h0 >> 16)), e1 * bf2f((ushort)(h1 >> 16)))
            + fmaf(e2, bf2f((ushort)(h2 >> 16)), e3 * bf2f((ushort)(h3 >> 16)));
    }
    for (; j < end; ++j) {
        int d = col_idx[j];
        float e = edge_e(si + s2dst[d]);
        u32 hv = *(const u32*)(h2p + (size_t)d * 128 + 2 * l);
        re += e;
        a0 = fmaf(e, bf2f((ushort)(hv & 0xffffu)), a0);
        a1 = fmaf(e, bf2f((ushort)(hv >> 16)), a1);
    }
    float inv = 1.f / (re + EPS_F);
    float v0 = a0 * inv, v1 = a1 * inv;
    v0 = v0 > 0.f ? v0 : expm1f(v0);
    v1 = v1 > 0.f ? v1 : expm1f(v1);
    int c0 = 2 * l, c1 = 2 * l + 1;
    bool val0 = c0 < 97, val1 = c1 < 97;
    float m = fmaxf(val0 ? v0 : -1e30f, val1 ? v1 : -1e30f);
#pragma unroll
    for (int o = 32; o; o >>= 1) m = fmaxf(m, __shfl_xor(m, o));
    float ex = (val0 ? __expf(v0 - m) : 0.f) + (val1 ? __expf(v1 - m) : 0.f);
#pragma unroll
    for (int o = 32; o; o >>= 1) ex += __shfl_xor(ex, o);
    float lt = m + logf(ex);
    if (val0) __builtin_nontemporal_store(v0 - lt, out + (size_t)w * 97 + c0);
    if (val1) __builtin_nontemporal_store(v1 - lt, out + (size_t)w * 97 + c1);
}

extern "C" void kernel_launch(void* const* d_in, const int* in_sizes, int n_in,
                              void* d_out, int out_size, void* d_ws, size_t ws_size,
                              hipStream_t stream)
{
    const float* feat = (const float*)d_in[0];   // [N,256] f32
    const float* W    = (const float*)d_in[1];   // [8,256,64] f32
    const float* a    = (const float*)d_in[2];   // [8,128] f32
    const float* Wout = (const float*)d_in[3];   // [512,97] f32
    const float* aout = (const float*)d_in[4];   // [194] f32
    const int*   ei   = (const int*)d_in[5];     // [2,E] int32
    float* out = (float*)d_out;                  // [N,97] f32

    const int N = N_NODES, E = N_EDGES;
    const int NB = (N + 255) / 256;  // 391

    // workspace layout with lifetime aliasing
    char* base = (char*)d_ws;
    ushort* h_all = (ushort*)(base);                 // 102,400,000 B  [gemm1 .. ea1]
    ushort* x1    = (ushort*)(base + 102400000);     // 102,400,000 B  [ea1 .. gemm2]
    ushort* featb = (ushort*)(base + 204800000);     // 51,200,000 B   [conv .. gemm1]
    ushort* h2p   = (ushort*)(base + 204800000);     // 25,600,000 B   [gemm2 .. ea2] (aliases featb)
    char* tail = base + 256000000;
    float* ssrc1   = (float*)(tail + 0);             // 3,200,000  [N][8]
    float* sdst1   = (float*)(tail + 3200000);       // 3,200,000  [N][8]
    float* s2src   = (float*)(tail + 6400000);       // 400,000
    float* s2dst   = (float*)(tail + 6800000);       // 400,000   (scores: one contiguous 7.2MB zero region)
    int*   row_ptr = (int*)(tail + 7200000);         // 400,128
    int*   cnt     = (int*)(tail + 7600128);         // 400,000
    int*   col_idx = (int*)(tail + 8000128);         // 6,400,000
    int*   bsum    = (int*)(tail + 14400128);        // 1,792
    ushort* Bp1    = (ushort*)(tail + 14401920);     // 262,144
    ushort* Bp2    = (ushort*)(tail + 14664064);     // 131,072
    float* acol1   = (float*)(tail + 14795136);      // 4,096
    float* acol2   = (float*)(tail + 14799232);      // 1,024
    int*   srow    = (int*)(tail + 14800256);        // 6,400,000 (ends at tail+21,200,256)

    hipMemsetAsync(cnt, 0, (size_t)N * 4, stream);
    hipMemsetAsync(ssrc1, 0, (size_t)7200000, stream);  // ssrc1+sdst1+s2src+s2dst
    conv_feat<<<(N * 256 / 4 + 255) / 256, 256, 0, stream>>>(feat, featb, N * 256 / 4);
    pretranspose<<<512, 256, 0, stream>>>(W, Wout, a, aout, Bp1, Bp2, acol1, acol2);

    // layer 1 projection (+ fused per-head score reduction)
    gemm_mfma<<<dim3(782, 4), 256, 0, stream>>>(featb, Bp1, h_all, acol1, ssrc1, sdst1, 8, N, 256, 512);

    // CSR
    hist<<<(E + 255) / 256, 256, 0, stream>>>(ei, cnt, E);
    scan_partial<<<NB, 256, 0, stream>>>(cnt, bsum, N);
    scan_block<<<1, 512, 0, stream>>>(bsum, NB);
    scan_final<<<NB, 256, 0, stream>>>(cnt, bsum, row_ptr, N, E);
    hipMemsetAsync(cnt, 0, (size_t)N * 4, stream);
    fill_csr<<<(E + 255) / 256, 256, 0, stream>>>(ei, row_ptr, cnt, col_idx, srow, E);

    // layer 1 aggregation (wave per node, inline scores)
    ea1<<<N / 4, 256, 0, stream>>>(row_ptr, col_idx, h_all, ssrc1, sdst1, x1);

    // layer 2
    gemm_mfma<<<dim3(782, 1), 256, 0, stream>>>(x1, Bp2, h2p, acol2, s2src, s2dst, 1, N, 512, 128);
    ea2<<<N / 4, 256, 0, stream>>>(row_ptr, col_idx, h2p, s2src, s2dst, out);
}

// Round 6
// 825.232 us; speedup vs baseline: 1.2396x; 1.0488x over previous
//
#include <hip/hip_runtime.h>
#include <hip/hip_bf16.h>
#include <stdint.h>

typedef __attribute__((ext_vector_type(8))) short short8;
typedef __attribute__((ext_vector_type(4))) float floatx4;
typedef uint32_t u32;

#define N_NODES 100000
#define N_EDGES 1600000
#define ALPHA_SLOPE 0.2f
#define EPS_F 1e-16f

static __device__ __forceinline__ float bf2f(ushort h) {
    u32 u = ((u32)h) << 16;
    return __builtin_bit_cast(float, u);
}
static __device__ __forceinline__ ushort f2bf(float f) {
    u32 u = __builtin_bit_cast(u32, f);
    u32 r = (u + 0x7fffu + ((u >> 16) & 1u)) >> 16;
    return (ushort)r;
}
static __device__ __forceinline__ float edge_e(float s) {
    float lr = s > 0.f ? s : ALPHA_SLOPE * s;
    return __expf(-lr);
}

// ---------------- fused prep: feat f32->bf16 | weight pretranspose | degree histogram ----------------
// blocks [0,25000): conv_feat; [25000,25512): pretranspose+acol; [25512,31762): hist.
__global__ __launch_bounds__(256) void prep(
    const float* __restrict__ feat, const float* __restrict__ W,
    const float* __restrict__ Wout, const float* __restrict__ a,
    const float* __restrict__ aout, const int* __restrict__ ei,
    ushort* __restrict__ featb, ushort* __restrict__ Bp1, ushort* __restrict__ Bp2,
    float* __restrict__ acol1, float* __restrict__ acol2, int* __restrict__ cnt)
{
    int b = blockIdx.x;
    if (b < 25000) {
        int i = b * 256 + threadIdx.x;          // n4 = 6,400,000 exact
        float4 v = ((const float4*)feat)[i];
        ushort4 o;
        o.x = f2bf(v.x); o.y = f2bf(v.y); o.z = f2bf(v.z); o.w = f2bf(v.w);
        ((ushort4*)featb)[i] = o;
    } else if (b < 25512) {
        int idx = (b - 25000) * 256 + threadIdx.x;
        if (idx < 256 * 512) {  // Bp1: K=256, N=512
            int k = idx >> 9, n = idx & 511;
            int head = n >> 6, c = n & 63;
            Bp1[((size_t)(k >> 3) * 512 + n) * 8 + (k & 7)] = f2bf(W[head * 16384 + k * 64 + c]);
        }
        if (idx < 512 * 128) {  // Bp2: K=512, N=97 padded to 128
            int k = idx >> 7, n = idx & 127;
            ushort v = (n < 97) ? f2bf(Wout[k * 97 + n]) : (ushort)0;
            Bp2[((size_t)(k >> 3) * 128 + n) * 8 + (k & 7)] = v;
        }
        if (idx < 512) {
            int head = idx >> 6, c = idx & 63;
            acol1[idx * 2]     = a[head * 128 + c];
            acol1[idx * 2 + 1] = a[head * 128 + 64 + c];
        }
        if (idx < 128) {
            acol2[idx * 2]     = (idx < 97) ? aout[idx] : 0.f;
            acol2[idx * 2 + 1] = (idx < 97) ? aout[97 + idx] : 0.f;
        }
    } else {
        int e = (b - 25512) * 256 + threadIdx.x;  // E = 1,600,000 exact
        atomicAdd(&cnt[ei[e]], 1);
    }
}

// ---------------- MFMA GEMM + fused score epilogue ----------------
// grid (NP/128, M/128): blockIdx.x = col tile (fast), blockIdx.y = row tile -> A panel L2 reuse.
// BK=64, LDS [kq 0..7][r^kq][8] xor-swizzle (conflict-free ds_write_b128, 2-way-free reads).
__global__ __launch_bounds__(256) void gemm_mfma(
    const ushort* __restrict__ A, const ushort* __restrict__ Bp,
    ushort* __restrict__ C, const float* __restrict__ acol,
    float* __restrict__ ssrc_arr, float* __restrict__ sdst_arr,
    int sstride, int M, int K, int NP)
{
    __shared__ __align__(16) ushort Ald[8 * 128 * 8];  // 16 KB
    const int tid = threadIdx.x;
    const int lane = tid & 63;
    const int wave = tid >> 6;
    const int wr = wave >> 1, wc = wave & 1;
    const int row0 = blockIdx.y * 128;
    const int col0 = blockIdx.x * 128;
    const int quad = lane >> 4;
    const int l16 = lane & 15;

    floatx4 acc[4][4] = {};

    for (int k0 = 0; k0 < K; k0 += 64) {
        __syncthreads();
#pragma unroll
        for (int i = 0; i < 4; ++i) {
            int q = i * 256 + tid;          // 1024 chunks of 16B: r = q>>3, kq = q&7
            int r = q >> 3, kq = q & 7;
            int row = row0 + r;
            if (row >= M) row = M - 1;      // clamp: garbage rows never stored
            const uint4* src = (const uint4*)(A + (size_t)row * K + k0 + kq * 8);
            *(uint4*)(&Ald[(kq * 128 + (r ^ kq)) * 8]) = *src;
        }
        __syncthreads();

#pragma unroll
        for (int s = 0; s < 2; ++s) {
            int kqq = s * 4 + quad;
            int kqg = (k0 >> 3) + kqq;
            short8 bfrag[4];
#pragma unroll
            for (int nt = 0; nt < 4; ++nt) {
                int col = col0 + wc * 64 + nt * 16 + l16;
                bfrag[nt] = *(const short8*)(Bp + ((size_t)kqg * NP + col) * 8);
            }
#pragma unroll
            for (int mt = 0; mt < 4; ++mt) {
                int r = wr * 64 + mt * 16 + l16;
                short8 afrag = *(const short8*)(&Ald[(kqq * 128 + (r ^ kqq)) * 8]);
#pragma unroll
                for (int nt = 0; nt < 4; ++nt) {
                    acc[mt][nt] = __builtin_amdgcn_mfma_f32_16x16x32_bf16(afrag, bfrag[nt], acc[mt][nt], 0, 0, 0);
                }
            }
        }
    }

    // C store
#pragma unroll
    for (int mt = 0; mt < 4; ++mt) {
#pragma unroll
        for (int rr = 0; rr < 4; ++rr) {
            int row = row0 + wr * 64 + mt * 16 + quad * 4 + rr;
            if (row < M) {
#pragma unroll
                for (int nt = 0; nt < 4; ++nt) {
                    int col = col0 + wc * 64 + nt * 16 + l16;
                    C[(size_t)row * NP + col] = f2bf(acc[mt][nt][rr]);
                }
            }
        }
    }

    // fused score epilogue: this wave covers one 64-col group g
    float av1[4], av2[4];
#pragma unroll
    for (int nt = 0; nt < 4; ++nt) {
        int col = col0 + wc * 64 + nt * 16 + l16;
        av1[nt] = acol[col * 2];
        av2[nt] = acol[col * 2 + 1];
    }
    int g = (col0 + wc * 64) >> 6;
    int goff = (sstride > 1) ? g : 0;
#pragma unroll
    for (int mt = 0; mt < 4; ++mt) {
#pragma unroll
        for (int rr = 0; rr < 4; ++rr) {
            float p1 = 0.f, p2 = 0.f;
#pragma unroll
            for (int nt = 0; nt < 4; ++nt) {
                p1 = fmaf(acc[mt][nt][rr], av1[nt], p1);
                p2 = fmaf(acc[mt][nt][rr], av2[nt], p2);
            }
#pragma unroll
            for (int o = 1; o < 16; o <<= 1) {
                p1 += __shfl_xor(p1, o);
                p2 += __shfl_xor(p2, o);
            }
            int row = row0 + wr * 64 + mt * 16 + quad * 4 + rr;
            if (l16 == 0 && row < M) {
                atomicAdd(&ssrc_arr[(size_t)row * sstride + goff], p1);
                atomicAdd(&sdst_arr[(size_t)row * sstride + goff], p2);
            }
        }
    }
}

// ---------------- CSR scans ----------------
__global__ __launch_bounds__(256) void scan_partial(const int* __restrict__ cnt, int* __restrict__ bsum, int N) {
    int idx = blockIdx.x * 256 + threadIdx.x;
    int v = (idx < N) ? cnt[idx] : 0;
#pragma unroll
    for (int o = 32; o; o >>= 1) v += __shfl_xor(v, o);
    __shared__ int ws[4];
    if ((threadIdx.x & 63) == 0) ws[threadIdx.x >> 6] = v;
    __syncthreads();
    if (threadIdx.x == 0) bsum[blockIdx.x] = ws[0] + ws[1] + ws[2] + ws[3];
}

__global__ __launch_bounds__(512) void scan_block(int* __restrict__ bsum, int nb) {
    __shared__ int s[512];
    int t = threadIdx.x;
    int v = (t < nb) ? bsum[t] : 0;
    s[t] = v;
    __syncthreads();
    for (int o = 1; o < 512; o <<= 1) {
        int u = (t >= o) ? s[t - o] : 0;
        __syncthreads();
        s[t] += u;
        __syncthreads();
    }
    if (t < nb) bsum[t] = s[t] - v;  // exclusive
}

__global__ __launch_bounds__(256) void scan_final(
    const int* __restrict__ cnt, const int* __restrict__ bsum,
    int* __restrict__ row_ptr, int N, int E)
{
    int b = blockIdx.x, t = threadIdx.x;
    int idx = b * 256 + t;
    int v = (idx < N) ? cnt[idx] : 0;
    __shared__ int s[256];
    s[t] = v;
    __syncthreads();
    for (int o = 1; o < 256; o <<= 1) {
        int u = (t >= o) ? s[t - o] : 0;
        __syncthreads();
        s[t] += u;
        __syncthreads();
    }
    if (idx < N) row_ptr[idx] = bsum[b] + s[t] - v;
    if (idx == 0) row_ptr[N] = E;
}

// fill CSR (col_idx only)
__global__ __launch_bounds__(256) void fill_csr(
    const int* __restrict__ ei, const int* __restrict__ row_ptr,
    int* __restrict__ cur, int* __restrict__ col_idx, int E)
{
    int e = blockIdx.x * 256 + threadIdx.x;
    if (e >= E) return;
    int s = ei[e];
    int d = ei[E + e];
    int p = atomicAdd(&cur[s], 1);
    col_idx[row_ptr[s] + p] = d;
}

// ---------------- layer-1 edge aggregation (inline scores) + normalize + ELU ----------------
// wave per node; lane owns 8 contiguous cols (head hl = l>>3); e computed per lane.
__global__ __launch_bounds__(256) void ea1(
    const int* __restrict__ row_ptr, const int* __restrict__ col_idx,
    const ushort* __restrict__ h_all, const float* __restrict__ ssrc1,
    const float* __restrict__ sdst1, ushort* __restrict__ x1)
{
    int w = blockIdx.x * 4 + (threadIdx.x >> 6);   // node
    int l = threadIdx.x & 63;
    int hl = l >> 3;
    int start = row_ptr[w], end = row_ptr[w + 1];
    float si = ssrc1[(size_t)w * 8 + hl];
    float acc[8] = {};
    float re = 0.f;
    int j = start;
    for (; j + 4 <= end; j += 4) {
        int d0 = col_idx[j], d1 = col_idx[j + 1], d2 = col_idx[j + 2], d3 = col_idx[j + 3];
        float e0 = edge_e(si + sdst1[(size_t)d0 * 8 + hl]);
        float e1 = edge_e(si + sdst1[(size_t)d1 * 8 + hl]);
        float e2 = edge_e(si + sdst1[(size_t)d2 * 8 + hl]);
        float e3 = edge_e(si + sdst1[(size_t)d3 * 8 + hl]);
        short8 v0 = *(const short8*)(h_all + (size_t)d0 * 512 + l * 8);
        short8 v1 = *(const short8*)(h_all + (size_t)d1 * 512 + l * 8);
        short8 v2 = *(const short8*)(h_all + (size_t)d2 * 512 + l * 8);
        short8 v3 = *(const short8*)(h_all + (size_t)d3 * 512 + l * 8);
        re += (e0 + e1) + (e2 + e3);
#pragma unroll
        for (int q = 0; q < 8; ++q) {
            float t0 = fmaf(e0, bf2f((ushort)v0[q]), e1 * bf2f((ushort)v1[q]));
            float t1 = fmaf(e2, bf2f((ushort)v2[q]), e3 * bf2f((ushort)v3[q]));
            acc[q] += t0 + t1;
        }
    }
    for (; j < end; ++j) {
        int d = col_idx[j];
        float e = edge_e(si + sdst1[(size_t)d * 8 + hl]);
        short8 hv = *(const short8*)(h_all + (size_t)d * 512 + l * 8);
        re += e;
#pragma unroll
        for (int q = 0; q < 8; ++q)
            acc[q] = fmaf(e, bf2f((ushort)hv[q]), acc[q]);
    }
    float inv = 1.f / (re + EPS_F);
    short8 o;
#pragma unroll
    for (int q = 0; q < 8; ++q) {
        float p = acc[q] * inv;
        p = p > 0.f ? p : expm1f(p);
        o[q] = (short)f2bf(p);
    }
    __builtin_nontemporal_store(o, (short8*)(x1 + (size_t)w * 512 + l * 8));
}

// ---------------- layer-2 aggregation (inline scores) + ELU + log_softmax ----------------
// HALF-wave (32 lanes) per node; lane owns cols 4l..4l+3. Halves redundant exp vs wave/node.
__global__ __launch_bounds__(256) void ea2(
    const int* __restrict__ row_ptr, const int* __restrict__ col_idx,
    const ushort* __restrict__ h2p, const float* __restrict__ s2src,
    const float* __restrict__ s2dst, float* __restrict__ out)
{
    int w = blockIdx.x * 8 + (threadIdx.x >> 5);
    int l = threadIdx.x & 31;
    int start = row_ptr[w], end = row_ptr[w + 1];
    float si = s2src[w];
    float a0 = 0.f, a1 = 0.f, a2 = 0.f, a3 = 0.f, re = 0.f;
    int j = start;
    for (; j + 4 <= end; j += 4) {
        int d0 = col_idx[j], d1 = col_idx[j + 1], d2 = col_idx[j + 2], d3 = col_idx[j + 3];
        float e0 = edge_e(si + s2dst[d0]);
        float e1 = edge_e(si + s2dst[d1]);
        float e2 = edge_e(si + s2dst[d2]);
        float e3 = edge_e(si + s2dst[d3]);
        ushort4 h0 = *(const ushort4*)(h2p + (size_t)d0 * 128 + 4 * l);
        ushort4 h1 = *(const ushort4*)(h2p + (size_t)d1 * 128 + 4 * l);
        ushort4 h2 = *(const ushort4*)(h2p + (size_t)d2 * 128 + 4 * l);
        ushort4 h3 = *(const ushort4*)(h2p + (size_t)d3 * 128 + 4 * l);
        re += (e0 + e1) + (e2 + e3);
        a0 += fmaf(e0, bf2f(h0.x), e1 * bf2f(h1.x)) + fmaf(e2, bf2f(h2.x), e3 * bf2f(h3.x));
        a1 += fmaf(e0, bf2f(h0.y), e1 * bf2f(h1.y)) + fmaf(e2, bf2f(h2.y), e3 * bf2f(h3.y));
        a2 += fmaf(e0, bf2f(h0.z), e1 * bf2f(h1.z)) + fmaf(e2, bf2f(h2.z), e3 * bf2f(h3.z));
        a3 += fmaf(e0, bf2f(h0.w), e1 * bf2f(h1.w)) + fmaf(e2, bf2f(h2.w), e3 * bf2f(h3.w));
    }
    for (; j < end; ++j) {
        int d = col_idx[j];
        float e = edge_e(si + s2dst[d]);
        ushort4 hv = *(const ushort4*)(h2p + (size_t)d * 128 + 4 * l);
        re += e;
        a0 = fmaf(e, bf2f(hv.x), a0);
        a1 = fmaf(e, bf2f(hv.y), a1);
        a2 = fmaf(e, bf2f(hv.z), a2);
        a3 = fmaf(e, bf2f(hv.w), a3);
    }
    float inv = 1.f / (re + EPS_F);
    float v[4] = { a0 * inv, a1 * inv, a2 * inv, a3 * inv };
    bool val[4];
    float m = -1e30f;
#pragma unroll
    for (int q = 0; q < 4; ++q) {
        v[q] = v[q] > 0.f ? v[q] : expm1f(v[q]);
        val[q] = (4 * l + q) < 97;
        if (val[q]) m = fmaxf(m, v[q]);
    }
#pragma unroll
    for (int o = 16; o; o >>= 1) m = fmaxf(m, __shfl_xor(m, o));  // 32-lane reduce
    float ex = 0.f;
#pragma unroll
    for (int q = 0; q < 4; ++q) ex += val[q] ? __expf(v[q] - m) : 0.f;
#pragma unroll
    for (int o = 16; o; o >>= 1) ex += __shfl_xor(ex, o);
    float lt = m + logf(ex);
#pragma unroll
    for (int q = 0; q < 4; ++q)
        if (val[q]) __builtin_nontemporal_store(v[q] - lt, out + (size_t)w * 97 + 4 * l + q);
}

extern "C" void kernel_launch(void* const* d_in, const int* in_sizes, int n_in,
                              void* d_out, int out_size, void* d_ws, size_t ws_size,
                              hipStream_t stream)
{
    const float* feat = (const float*)d_in[0];   // [N,256] f32
    const float* W    = (const float*)d_in[1];   // [8,256,64] f32
    const float* a    = (const float*)d_in[2];   // [8,128] f32
    const float* Wout = (const float*)d_in[3];   // [512,97] f32
    const float* aout = (const float*)d_in[4];   // [194] f32
    const int*   ei   = (const int*)d_in[5];     // [2,E] int32
    float* out = (float*)d_out;                  // [N,97] f32

    const int N = N_NODES, E = N_EDGES;
    const int NB = (N + 255) / 256;  // 391

    // workspace layout with lifetime aliasing
    char* base = (char*)d_ws;
    ushort* h_all = (ushort*)(base);                 // 102,400,000 B  [gemm1 .. ea1]
    ushort* x1    = (ushort*)(base + 102400000);     // 102,400,000 B  [ea1 .. gemm2]
    ushort* featb = (ushort*)(base + 204800000);     // 51,200,000 B   [prep .. gemm1]
    ushort* h2p   = (ushort*)(base + 204800000);     // 25,600,000 B   [gemm2 .. ea2] (aliases featb)
    char* tail = base + 256000000;
    float* ssrc1   = (float*)(tail + 0);             // 3,200,000  [N][8]
    float* sdst1   = (float*)(tail + 3200000);       // 3,200,000  [N][8]
    float* s2src   = (float*)(tail + 6400000);       // 400,000
    float* s2dst   = (float*)(tail + 6800000);       // 400,000
    int*   row_ptr = (int*)(tail + 7200000);         // 400,128
    int*   cnt     = (int*)(tail + 7600128);         // 400,000
    int*   cur     = (int*)(tail + 8000128);         // 400,000   <- one memset covers tail..8,400,128
    int*   col_idx = (int*)(tail + 8400128);         // 6,400,000
    int*   bsum    = (int*)(tail + 14800128);        // 1,792
    ushort* Bp1    = (ushort*)(tail + 14801920);     // 262,144
    ushort* Bp2    = (ushort*)(tail + 15064064);     // 131,072
    float* acol1   = (float*)(tail + 15195136);      // 4,096
    float* acol2   = (float*)(tail + 15199232);      // 1,024   (ends tail+15,200,256)

    // single zero-fill: scores + row_ptr + cnt + cur
    hipMemsetAsync(ssrc1, 0, (size_t)8400128, stream);

    // fused prep: feat conversion + weight pretranspose + degree histogram
    prep<<<31762, 256, 0, stream>>>(feat, W, Wout, a, aout, ei, featb, Bp1, Bp2, acol1, acol2, cnt);

    // layer 1 projection (+ fused per-head score reduction); grid (col,row) for A-panel L2 reuse
    gemm_mfma<<<dim3(4, 782), 256, 0, stream>>>(featb, Bp1, h_all, acol1, ssrc1, sdst1, 8, N, 256, 512);

    // CSR
    scan_partial<<<NB, 256, 0, stream>>>(cnt, bsum, N);
    scan_block<<<1, 512, 0, stream>>>(bsum, NB);
    scan_final<<<NB, 256, 0, stream>>>(cnt, bsum, row_ptr, N, E);
    fill_csr<<<(E + 255) / 256, 256, 0, stream>>>(ei, row_ptr, cur, col_idx, E);

    // layer 1 aggregation (wave per node, inline scores)
    ea1<<<N / 4, 256, 0, stream>>>(row_ptr, col_idx, h_all, ssrc1, sdst1, x1);

    // layer 2
    gemm_mfma<<<dim3(1, 782), 256, 0, stream>>>(x1, Bp2, h2p, acol2, s2src, s2dst, 1, N, 512, 128);
    ea2<<<N / 8, 256, 0, stream>>>(row_ptr, col_idx, h2p, s2src, s2dst, out);
}